// Round 8
// baseline (484.773 us; speedup 1.0000x reference)
//
#include <hip/hip_runtime.h>

#define N_  16
#define T_  1024
#define D_  2000
#define K_  21
#define P_  10
#define NT_ (N_*T_)   // 16384
#define SL  250       // d-slice width (8 slices; 4 slices per channel group)
#define RB  128       // rows per k_coef block
#define PIT 129       // LDS column pitch (odd -> conflict-free scatter writes)

// ---------------- K0: pad W rows [D][21] -> [D][24] (aligned rows) --------
__global__ void k_padW(const float* __restrict__ W0, const float* __restrict__ W1,
                       float* __restrict__ W0p, float* __restrict__ W1p) {
    int gid = blockIdx.x * blockDim.x + threadIdx.x;
    if (gid >= D_ * 24) return;
    int d = gid / 24, kk = gid - d * 24;
    W0p[gid] = (kk < K_) ? W0[d * K_ + kk] : 0.f;
    W1p[gid] = (kk < K_) ? W1[d * K_ + kk] : 0.f;
}

// ---------------- K1: coefficient GEMM ------------------------------------
// grid 1024 = 128 row-groups (128 rows) x 8 d-slices (250 wide).
// Waves 0,1 -> W0 products; waves 2,3 -> W1 (halves W traffic per wave).
// Lane owns 2 rows (x via one LDS float2) -> 42 FMA per 21 W-dwords.
// x staged coalesced f2 -> column-major LDS tile [32 c][PIT rows], dbuf.
__global__ __launch_bounds__(256, 4)
void k_coef(const float* __restrict__ x,
            const float* __restrict__ W0p, const float* __restrict__ W1p,
            float* __restrict__ qb, float* __restrict__ mpb) {
    __shared__ float lds[2 * 32 * PIT];    // 33 KB; reduce overlay needs 5376
    const int tid  = threadIdx.x;
    const int lane = tid & 63;
    const int w    = __builtin_amdgcn_readfirstlane(tid >> 6);
    const int rg   = blockIdx.x >> 3;      // 0..127
    const int s    = blockIdx.x & 7;       // slice
    const int r0   = rg * RB;
    const int d0   = s * SL;

    float acc[2][K_];
#pragma unroll
    for (int k = 0; k < K_; ++k) { acc[0][k] = 0.f; acc[1][k] = 0.f; }

    // staging: lane group reads 128B contiguous per row; 8 row-passes
    const int sc2 = (tid & 15) * 2;        // even col 0..30
    const int srw = tid >> 4;              // 0..15
    float2 rv[8];

    auto load_tile = [&](int ct) {
#pragma unroll
        for (int p = 0; p < 8; ++p) {
            const int col = ct + sc2;
            const float* px = x + (size_t)(r0 + srw + p * 16) * D_ + d0 + col;
            rv[p] = (col < SL) ? *reinterpret_cast<const float2*>(px)
                               : make_float2(0.f, 0.f);
        }
    };
    auto write_tile = [&](int buf) {
        float* b = lds + buf * (32 * PIT);
#pragma unroll
        for (int p = 0; p < 8; ++p) {
            b[sc2 * PIT + srw + p * 16]       = rv[p].x;
            b[(sc2 + 1) * PIT + srw + p * 16] = rv[p].y;
        }
    };

    const float* __restrict__ Wsel = (w < 2) ? W0p : W1p;
    const int cbase = (w & 1) * 16;

    load_tile(0);
    write_tile(0);
    __syncthreads();

    for (int t = 0; t < 8; ++t) {
        if (t < 7) load_tile((t + 1) * 32);
        const float* xs = lds + (t & 1) * (32 * PIT);
        const int cw = (t < 7) ? 32 : (SL - 224);       // 26 on tail
        int dbase;                                      // VGPR-forced tile base
        asm("v_mov_b32 %0, %1" : "=v"(dbase) : "s"(d0 + t * 32));
#pragma unroll
        for (int c = 0; c < 16; ++c) {
            const int cc = cbase + c;
            if (cc < cw) {                              // uniform (always true t<7)
                const float* wr = Wsel + (size_t)(dbase + cc) * 24;
                float wk[21];
#pragma unroll
                for (int j = 0; j < 5; ++j)
                    *reinterpret_cast<float4*>(&wk[4 * j]) =
                        *reinterpret_cast<const float4*>(wr + 4 * j);
                wk[20] = wr[20];
                const float2 xv =
                    *reinterpret_cast<const float2*>(xs + cc * PIT + 2 * lane);
#pragma unroll
                for (int k = 0; k < K_; ++k) {
                    acc[0][k] = fmaf(xv.x, wk[k], acc[0][k]);
                    acc[1][k] = fmaf(xv.y, wk[k], acc[1][k]);
                }
            }
        }
        if (t < 7) write_tile((t + 1) & 1);
        __syncthreads();
    }

    // reduce: waves {0,1} hold w0-partials, {2,3} hold W1-partials.
    float* red = lds;
    float* qs  = qb  + (size_t)s * (NT_ * K_);
    float* mps = mpb + (size_t)s * (NT_ * K_);
#define REDPASS(R)                                                              \
    do {                                                                        \
        __syncthreads();                                                        \
        _Pragma("unroll")                                                       \
        for (int k = 0; k < K_; ++k) red[tid * K_ + k] = acc[R][k];             \
        __syncthreads();                                                        \
        for (int o = tid; o < 64 * K_; o += 256) {                              \
            int l = o / K_, k = o - l * K_;                                     \
            size_t g = (size_t)(r0 + 2 * l + R) * K_ + k;                       \
            qs[g]  = red[o] + red[o + 64 * K_];                                 \
            mps[g] = red[o + 128 * K_] + red[o + 192 * K_];                     \
        }                                                                       \
    } while (0)
    REDPASS(0);
    REDPASS(1);
#undef REDPASS
}

// ---------------- K1.5: finalize w0, compute w1 (LDS-staged) ---------------
// w0 = sum_s qb[s] ; M = sum_{s<4} mpb[s] ; P = sum_{s>=4} mpb[s]
// w1[row,k] = P[row,k] + sum_j w0[row,j] * M[row+j-10, k]
__global__ __launch_bounds__(256)
void k_finish(const float* __restrict__ qb, const float* __restrict__ mpb,
              float* __restrict__ w0f, float* __restrict__ w1f) {
    __shared__ float w0s[64 * K_];
    __shared__ float Ms[84 * K_];
    const int tid = threadIdx.x;
    const int r0 = blockIdx.x * 64;
    const size_t CW = (size_t)NT_ * K_;

    for (int o = tid; o < 64 * K_; o += 256) {
        size_t g = (size_t)r0 * K_ + o;
        float v = 0.f;
#pragma unroll
        for (int ss = 0; ss < 8; ++ss) v += qb[ss * CW + g];
        w0s[o] = v;
    }
    for (int o = tid; o < 84 * K_; o += 256) {
        int i = o / K_, j = o - i * K_;
        int rr = r0 - P_ + i;
        float v = 0.f;
        if (rr >= 0 && rr < NT_) {
            size_t g = (size_t)rr * K_ + j;
            v = mpb[g] + mpb[CW + g] + mpb[2 * CW + g] + mpb[3 * CW + g];
        }
        Ms[o] = v;
    }
    __syncthreads();

    for (int o = tid; o < 64 * K_; o += 256) {
        int row = o / K_, k = o - row * K_;
        size_t g = (size_t)(r0 + row) * K_ + k;
        float accv = mpb[4 * CW + g] + mpb[5 * CW + g] +
                     mpb[6 * CW + g] + mpb[7 * CW + g];
        int t = (r0 + row) & (T_ - 1);
#pragma unroll
        for (int j = 0; j < K_; ++j) {
            int tt = t + j - P_;
            if (tt >= 0 && tt < T_)
                accv = fmaf(w0s[row * K_ + j], Ms[(row + j) * K_ + k], accv);
        }
        w1f[g] = accv;
        w0f[g] = w0s[o];
    }
}

// ---------------- K2/K3: shift-conv, sliding register window ---------------
// block = (grp, n, 64-t-chunk, 128-d-seg); 4 waves x 16 rows x 128 d (f2/lane).
// Coefs are wave-uniform -> scalar loads via constant cache (no LDS).
__global__ __launch_bounds__(256)
void k_conv(const float* __restrict__ x, const float* __restrict__ w0f,
            const float* __restrict__ w1f, float* __restrict__ out) {
    __shared__ float xsl[84][128];     // 43 KB
    const int b = blockIdx.x;
    const int dseg = b & 7;
    const int tch  = (b >> 3) & 15;
    const int nn   = (b >> 7) & 15;
    const int grp  = b >> 11;
    const float* __restrict__ coef = grp ? w1f : w0f;
    const int dbase = grp * 1000;
    const int t0 = tch * 64;
    const int tid = threadIdx.x;
    const float* xb = x + (size_t)nn * T_ * D_;

    {   // stage x halo tile [t0-10, t0+74) x 128 cols
        const int scol = tid & 31, srow0 = tid >> 5;
#pragma unroll
        for (int pass = 0; pass < 11; ++pass) {
            int rr = srow0 + pass * 8;
            if (rr < 84) {
                int u = t0 - P_ + rr;
                int dl = dseg * 128 + scol * 4;
                float4 v = make_float4(0.f, 0.f, 0.f, 0.f);
                if (u >= 0 && u < T_ && dl < 1000)
                    v = *reinterpret_cast<const float4*>(xb + (size_t)u * D_ + dbase + dl);
                *reinterpret_cast<float4*>(&xsl[rr][scol * 4]) = v;
            }
        }
    }
    __syncthreads();

    const int wv = __builtin_amdgcn_readfirstlane(tid >> 6);
    const int lane = tid & 63;
    const int rw = wv * 16;                      // wave's first output row (local)
    const int dcol = dseg * 128 + lane * 2;
    const bool act = (dcol < 1000);

    float2 win[21];                              // sliding window, static-indexed
#pragma unroll
    for (int ss = 0; ss < 21; ++ss)
        win[ss] = *reinterpret_cast<const float2*>(&xsl[rw + ss][lane * 2]);

    const float* __restrict__ crow =
        coef + ((size_t)nn * T_ + t0 + rw) * K_;   // wave-uniform base
    float* obase = out + ((size_t)nn * T_ + t0 + rw) * D_ + dbase + dcol;

#pragma unroll
    for (int i = 0; i < 16; ++i) {
        float2 a2 = make_float2(0.f, 0.f);
#pragma unroll
        for (int k = 0; k < K_; ++k) {
            const float c = crow[i * K_ + k];      // uniform -> s_load
            const float2 xv = win[(i + k) % 21];   // static index
            a2.x = fmaf(c, xv.x, a2.x);
            a2.y = fmaf(c, xv.y, a2.y);
        }
        if (act) *reinterpret_cast<float2*>(obase + (size_t)i * D_) = a2;
        if (i < 15)                                // slide window
            win[i % 21] = *reinterpret_cast<const float2*>(&xsl[rw + i + 21][lane * 2]);
    }
}

extern "C" void kernel_launch(void* const* d_in, const int* in_sizes, int n_in,
                              void* d_out, int out_size, void* d_ws, size_t ws_size,
                              hipStream_t stream) {
    const float* x  = (const float*)d_in[0];
    const float* W0 = (const float*)d_in[1];
    const float* W1 = (const float*)d_in[2];
    float* out = (float*)d_out;
    float* ws  = (float*)d_ws;

    const size_t CW = (size_t)NT_ * K_;     // 344064
    float* W0p = ws;                        // 48000
    float* W1p = ws + 48000;                // 48000
    float* qb  = ws + 96000;                // 8 * CW  (w0 partials per slice)
    float* mpb = qb + 8 * CW;               // 8 * CW  (W1 partials per slice)
    float* w0f = mpb + 8 * CW;              // CW
    float* w1f = w0f + CW;                  // CW   -- total ~25.2 MB

    hipLaunchKernelGGL(k_padW, dim3(188), dim3(256), 0, stream, W0, W1, W0p, W1p);
    hipLaunchKernelGGL(k_coef, dim3(1024), dim3(256), 0, stream,
                       x, W0p, W1p, qb, mpb);
    hipLaunchKernelGGL(k_finish, dim3(256), dim3(256), 0, stream,
                       qb, mpb, w0f, w1f);
    hipLaunchKernelGGL(k_conv, dim3(4096), dim3(256), 0, stream, x, w0f, w1f, out);
}